// Round 1
// baseline (126.606 us; speedup 1.0000x reference)
//
#include <hip/hip_runtime.h>

#define HH 256
#define WW 256
#define KK 4
#define TILE 16
#define HALO 18               // 16 + 1-pixel halo each side
#define NPIX (HALO*HALO)      // 324
#define NITEM (NPIX*KK)       // 1296
#define BIGF 1e10f
#define NORM_C 0.6503144f     // 1.05 / (1 + 4e^-2 + 4e^-4)

__global__ __launch_bounds__(256) void splat_phong(
    const float* __restrict__ texels,
    const float* __restrict__ normals,
    const float* __restrict__ pccam,
    const float* __restrict__ pcscr,
    const float* __restrict__ qdep,
    const int*   __restrict__ bgmask,
    const float* __restrict__ lpos,
    const float* __restrict__ lamb,
    const float* __restrict__ ldif,
    const float* __restrict__ lspec,
    const float* __restrict__ campos,
    const float* __restrict__ mamb,
    const float* __restrict__ mdif,
    const float* __restrict__ mspec,
    float* __restrict__ out)
{
    __shared__ float4 s_rgba[NITEM];
    __shared__ float  s_jy[NITEM];
    __shared__ float  s_jx[NITEM];
    __shared__ float  s_d [NITEM];

    const int n  = blockIdx.z;
    const int y0 = blockIdx.y * TILE;
    const int x0 = blockIdx.x * TILE;
    const int tid = threadIdx.x;

    // uniform small vectors (L2-resident; compiler scalarizes)
    const float lx0 = lpos[0],  ly0 = lpos[1],  lz0 = lpos[2];
    const float cx0 = campos[0], cy0 = campos[1], cz0 = campos[2];
    const float A0 = lamb[0]*mamb[0],  A1 = lamb[1]*mamb[1],  A2 = lamb[2]*mamb[2];
    const float D0 = ldif[0]*mdif[0],  D1 = ldif[1]*mdif[1],  D2 = ldif[2]*mdif[2];
    const float S0 = lspec[0]*mspec[0], S1 = lspec[1]*mspec[1], S2 = lspec[2]*mspec[2];

    // ---- Phase 1: shade the 18x18x4 halo into LDS (each item shaded ONCE) ----
    for (int it = tid; it < NITEM; it += 256) {
        const int k  = it & (KK-1);
        const int pi = it >> 2;
        const int hy = pi / HALO;
        const int hx = pi - hy*HALO;
        const int y = y0 - 1 + hy;
        const int x = x0 - 1 + hx;
        float4 rgba = make_float4(0.f, 0.f, 0.f, 0.f);
        float jy = 0.f, jx = 0.f, dep = BIGF;
        if ((unsigned)y < HH && (unsigned)x < WW) {
            const int base = ((n*HH + y)*WW + x)*KK + k;
            const float* nr = normals + (size_t)base*3;
            float nx = nr[0], ny = nr[1], nz = nr[2];
            float ri = rsqrtf(nx*nx + ny*ny + nz*nz + 1e-8f);
            nx *= ri; ny *= ri; nz *= ri;
            const float* pc = pccam + (size_t)base*3;
            const float px = pc[0], py = pc[1], pz = pc[2];
            float llx = lx0-px, lly = ly0-py, llz = lz0-pz;
            ri = rsqrtf(llx*llx + lly*lly + llz*llz + 1e-8f);
            llx *= ri; lly *= ri; llz *= ri;
            float vx = cx0-px, vy = cy0-py, vz = cz0-pz;
            ri = rsqrtf(vx*vx + vy*vy + vz*vz + 1e-8f);
            vx *= ri; vy *= ri; vz *= ri;
            const float ndl = nx*llx + ny*lly + nz*llz;
            const float rx = 2.f*ndl*nx - llx;
            const float ry = 2.f*ndl*ny - lly;
            const float rz = 2.f*ndl*nz - llz;
            float rdv = fmaxf(rx*vx + ry*vy + rz*vz, 0.f);
            const float p2 = rdv*rdv, p4 = p2*p2, p8 = p4*p4;
            const float p16 = p8*p8, p32 = p16*p16, p64 = p32*p32;
            const float ndlr = fmaxf(ndl, 0.f);
            const float* t3 = texels + (size_t)base*3;
            const float alpha = 1.f - (float)bgmask[base];
            rgba.x = t3[0]*(A0 + D0*ndlr) + S0*p64;
            rgba.y = t3[1]*(A1 + D1*ndlr) + S1*p64;
            rgba.z = t3[2]*(A2 + D2*ndlr) + S2*p64;
            rgba.w = alpha;                      // OOB stays alpha=0 -> zero splat
            jy = pcscr[(size_t)base*2+0] - ((float)y + 0.5f);
            jx = pcscr[(size_t)base*2+1] - ((float)x + 0.5f);
            dep = qdep[base];                    // OOB stays BIG (matches _shift pad)
        }
        s_rgba[it] = rgba;
        s_jy[it]   = jy;
        s_jx[it]   = jx;
        s_d[it]    = dep;
    }
    __syncthreads();

    // ---- Phase 2: one thread per output pixel, gather 9 neighbors x 4 layers ----
    const int ty = tid >> 4;
    const int tx = tid & 15;
    const int ob = ((ty+1)*HALO + (tx+1))*KK;
    const float q0 = s_d[ob], q1 = s_d[ob+1], q2 = s_d[ob+2], q3 = s_d[ob+3];

    float afg[5] = {0,0,0,0,0}, asf[5] = {0,0,0,0,0}, abg[5] = {0,0,0,0,0};

    #pragma unroll
    for (int d = 0; d < 9; ++d) {
        const int dy = d/3 - 1;
        const int dx = d - (d/3)*3 - 1;
        const int pb = ((ty+1-dy)*HALO + (tx+1-dx))*KK;   // neighbor p = gather - (dy,dx)
        const float pd0 = s_d[pb], pd1 = s_d[pb+1], pd2 = s_d[pb+2], pd3 = s_d[pb+3];
        const float ptop = pd0;
        // lq = argmin_k |p_top - q_k| (first-min, strict <), dq_min
        float dqm = fabsf(ptop - q0); int lq = 0;
        float t;
        t = fabsf(ptop - q1); if (t < dqm) { dqm = t; lq = 1; }
        t = fabsf(ptop - q2); if (t < dqm) { dqm = t; lq = 2; }
        t = fabsf(ptop - q3); if (t < dqm) { dqm = t; lq = 3; }
        // lp = argmin_k |q_top - p_k|, dp_min
        float dpm = fabsf(q0 - pd0); int lp = 0;
        t = fabsf(q0 - pd1); if (t < dpm) { dpm = t; lp = 1; }
        t = fabsf(q0 - pd2); if (t < dpm) { dpm = t; lp = 2; }
        t = fabsf(q0 - pd3); if (t < dpm) { dpm = t; lp = 3; }
        const int occ = (dqm <= dpm) ? lq : -lp;
        const float fdy = (float)dy, fdx = (float)dx;
        #pragma unroll
        for (int k = 0; k < KK; ++k) {
            const int level = k + occ;
            const float4 r = s_rgba[pb+k];
            const float ddy = s_jy[pb+k] - fdy;
            const float ddx = s_jx[pb+k] - fdx;
            // exp(-dist2 / (2*sigma^2)) with 2*sigma^2 = 0.5  ->  exp(-2*dist2)
            const float wgt = __expf(-2.0f*(ddy*ddy + ddx*ddx)) * NORM_C * r.w;
            const float wf = (level <  0) ? wgt : 0.f;
            const float ws = (level == 0) ? wgt : 0.f;
            const float wb = (level >  0) ? wgt : 0.f;
            afg[0] += r.x*wf; afg[1] += r.y*wf; afg[2] += r.z*wf; afg[3] += r.w*wf; afg[4] += wf;
            asf[0] += r.x*ws; asf[1] += r.y*ws; asf[2] += r.z*ws; asf[3] += r.w*ws; asf[4] += ws;
            abg[0] += r.x*wb; abg[1] += r.y*wb; abg[2] += r.z*wb; abg[3] += r.w*wb; abg[4] += wb;
        }
    }

    // normalize each class, composite bg <- surf <- fg, then over background color
    const float ifg = 1.f / fmaxf(afg[4], 1e-10f);
    const float isf = 1.f / fmaxf(asf[4], 1e-10f);
    const float ibg = 1.f / fmaxf(abg[4], 1e-10f);
    float o0 = abg[0]*ibg, o1 = abg[1]*ibg, o2 = abg[2]*ibg, o3 = abg[3]*ibg;
    const float sa = asf[3]*isf;
    o0 = asf[0]*isf + (1.f - sa)*o0;
    o1 = asf[1]*isf + (1.f - sa)*o1;
    o2 = asf[2]*isf + (1.f - sa)*o2;
    o3 = sa         + (1.f - sa)*o3;
    const float fa = afg[3]*ifg;
    o0 = afg[0]*ifg + (1.f - fa)*o0;
    o1 = afg[1]*ifg + (1.f - fa)*o1;
    o2 = afg[2]*ifg + (1.f - fa)*o2;
    o3 = fa         + (1.f - fa)*o3;
    const float bgc = 1.f - o3;   // BG_COLOR = (1,1,1)
    const float4 res = make_float4(o0 + bgc, o1 + bgc, o2 + bgc, o3);

    const int y = y0 + ty, x = x0 + tx;
    float4* op = (float4*)(out + (size_t)((n*HH + y)*WW + x)*4);
    *op = res;
}

extern "C" void kernel_launch(void* const* d_in, const int* in_sizes, int n_in,
                              void* d_out, int out_size, void* d_ws, size_t ws_size,
                              hipStream_t stream) {
    const int N = in_sizes[4] / (HH*WW*KK);   // q_depth is (N,H,W,K)
    dim3 grid(WW/TILE, HH/TILE, N);
    splat_phong<<<grid, dim3(256), 0, stream>>>(
        (const float*)d_in[0],   // texels
        (const float*)d_in[1],   // pixel_normals
        (const float*)d_in[2],   // pixel_coords_cameras
        (const float*)d_in[3],   // pixel_coords_screen
        (const float*)d_in[4],   // q_depth
        (const int*  )d_in[5],   // background_mask
        (const float*)d_in[6],   // light_position
        (const float*)d_in[7],   // light_ambient
        (const float*)d_in[8],   // light_diffuse
        (const float*)d_in[9],   // light_specular
        (const float*)d_in[10],  // camera_position
        (const float*)d_in[11],  // mat_ambient
        (const float*)d_in[12],  // mat_diffuse
        (const float*)d_in[13],  // mat_specular
        (float*)d_out);
}